// Round 11
// baseline (500.898 us; speedup 1.0000x reference)
//
#include <hip/hip_runtime.h>
#include <math.h>

#define HN 56
#define WN 56
#define LN 3136
#define BN 4
#define DIN 192
#define NST 16
#define KD 4
#define DTR 6
#define CPROJ 38
#define CL 56
#define NC 56
#define DMODEL 96

__device__ __forceinline__ float silu_f(float x){ return x / (1.0f + __expf(-x)); }
__device__ __forceinline__ float softplus_f(float x){ return (x > 20.0f) ? x : log1pf(__expf(x)); }

// sequence position s of direction k -> row-major spatial location
__device__ __forceinline__ int seq_to_loc(int k, int s){
  int ss = (k & 2) ? (LN - 1 - s) : s;
  if (k & 1) { int h = ss % HN; int w = ss / HN; return h * WN + w; }
  return ss;
}

// ---------------- K1: in_proj GEMM (12544 x 384, K=96) ----------------
__global__ __launch_bounds__(256) void k1_inproj(const float* __restrict__ x,
    const float* __restrict__ w, float* __restrict__ xi, float* __restrict__ sz){
  __shared__ float sx[32*100];   // padded stride 100 to avoid bank conflicts
  __shared__ float sw[96*100];
  int t = threadIdx.x;
  int m0 = blockIdx.x * 32;          // row tile
  int g  = blockIdx.y;               // col group: cols g*96 .. g*96+95
  const float* xb = x + (size_t)m0 * 96;
  const float* wb = w + (size_t)g * 96 * 96;
  for (int i = t; i < 32*96; i += 256) sx[(i/96)*100 + (i%96)] = xb[i];
  for (int i = t; i < 96*96; i += 256) sw[(i/96)*100 + (i%96)] = wb[i];
  __syncthreads();
  int li0 = (t & 7) * 4;
  int c0  = (t >> 3) * 3;
  float acc[4][3];
  #pragma unroll
  for (int j=0;j<4;j++){ acc[j][0]=0.f; acc[j][1]=0.f; acc[j][2]=0.f; }
  for (int i = 0; i < 96; i += 4) {
    float4 xv[4], wv[3];
    #pragma unroll
    for (int j=0;j<4;j++) xv[j] = *(const float4*)&sx[(li0+j)*100 + i];
    #pragma unroll
    for (int m=0;m<3;m++) wv[m] = *(const float4*)&sw[(c0+m)*100 + i];
    #pragma unroll
    for (int j=0;j<4;j++){
      #pragma unroll
      for (int m=0;m<3;m++){
        acc[j][m] += xv[j].x*wv[m].x + xv[j].y*wv[m].y + xv[j].z*wv[m].z + xv[j].w*wv[m].w;
      }
    }
  }
  #pragma unroll
  for (int j=0;j<4;j++){
    int row = m0 + li0 + j;
    #pragma unroll
    for (int m=0;m<3;m++){
      int o = g*96 + c0 + m;
      float v = acc[j][m];
      if (o < DIN) xi[(size_t)row*DIN + o] = v;
      else         sz[(size_t)row*DIN + (o - DIN)] = silu_f(v);
    }
  }
}

// ---------------- K2: depthwise conv 3x3 + silu; also y_init = xc * sum_k D ----------------
__global__ __launch_bounds__(256) void k2_conv(const float* __restrict__ xi,
    const float* __restrict__ cw, const float* __restrict__ cb,
    const float* __restrict__ Ds,
    float* __restrict__ xc, float* __restrict__ ysum){
  int t = blockIdx.x * 256 + threadIdx.x;
  const int total = BN * LN * (DIN/4);
  if (t >= total) return;
  int c4 = t % (DIN/4); int m = t / (DIN/4);
  int c = c4 * 4;
  int b = m / LN; int loc = m % LN;
  int h = loc / WN; int w = loc % WN;
  float acc[4];
  #pragma unroll
  for (int j=0;j<4;j++) acc[j] = cb[c+j];
  float wgt[4][9];
  #pragma unroll
  for (int j=0;j<4;j++)
    #pragma unroll
    for (int q=0;q<9;q++) wgt[j][q] = cw[(c+j)*9 + q];
  for (int dh=-1; dh<=1; dh++){
    int hh = h + dh; if (hh < 0 || hh >= HN) continue;
    for (int dw=-1; dw<=1; dw++){
      int ww = w + dw; if (ww < 0 || ww >= WN) continue;
      const float4 xv = *(const float4*)&xi[((size_t)(b*LN + hh*WN + ww))*DIN + c];
      int q = (dh+1)*3 + (dw+1);
      acc[0] += xv.x * wgt[0][q];
      acc[1] += xv.y * wgt[1][q];
      acc[2] += xv.z * wgt[2][q];
      acc[3] += xv.w * wgt[3][q];
    }
  }
  float4 xcv, yv;
  #pragma unroll
  for (int j=0;j<4;j++){
    float v = silu_f(acc[j]);
    float sd = Ds[c+j] + Ds[DIN + c+j] + Ds[2*DIN + c+j] + Ds[3*DIN + c+j];
    ((float*)&xcv)[j] = v;
    ((float*)&yv)[j]  = v * sd;
  }
  *(float4*)&xc[(size_t)m*DIN + c]   = xcv;
  *(float4*)&ysum[(size_t)m*DIN + c] = yv;
}

// ---------------- K3 v4: x_proj (38x192) + dt_proj + softplus ----------------
// No W/X LDS staging at all: W reads are colg-merged (8 unique addrs/wave-instr,
// L2-resident 29KB), X reads rowg-merged. 32-loc tiles -> grid 1568 (6.1 blk/CU);
// LDS only 8.7KB; launch_bounds(256,6) keeps 6 waves/SIMD resident for latency hiding.
// R9/R10 lesson: this op is bound by wave residency, not LDS bandwidth.
__global__ __launch_bounds__(256, 6) void k3_proj(const float* __restrict__ xc,
    const float* __restrict__ xpw,   // (4,38,192)
    const float* __restrict__ dtw,   // (4,192,6)
    const float* __restrict__ dtb,   // (4,192)
    float* __restrict__ delta, float* __restrict__ Bsp, float* __restrict__ Csp){
  __shared__ float sdt[DTR*DIN]; // transposed dt_projs_weight
  __shared__ float sp[32*8];
  int t = threadIdx.x;
  int loc0 = blockIdx.x * 32;
  int b = blockIdx.y;
  int k = blockIdx.z;
  int kb = k*BN + b;
  // stage dtw transposed: sdt[r][d] = dtw[d][r]
  const float* dtwk = dtw + (size_t)k*DIN*DTR;
  for (int f = t; f < DIN*DTR; f += 256){
    int d = f / DTR, r = f % DTR;
    sdt[r*DIN + d] = dtwk[f];
  }
  int rowg = t >> 3;   // 0..31 -> one loc each
  int colg = t & 7;    // 0..7  -> cols colg*5 .. colg*5+4 (guarded)
  float acc[5];
  #pragma unroll
  for (int c=0;c<5;c++) acc[c] = 0.f;
  const float* xr = xc + ((size_t)b*LN + loc0 + rowg)*DIN;
  const float* wk = xpw + (size_t)k*CPROJ*DIN;
  const float* wp[5];
  #pragma unroll
  for (int c=0;c<5;c++){
    int col = colg*5 + c;
    wp[c] = wk + (size_t)(col < CPROJ ? col : 0)*DIN;  // clamp OOB cols to row 0 (discarded)
  }
  for (int i = 0; i < 48; i++){
    float4 xv = *(const float4*)&xr[i*4];
    #pragma unroll
    for (int c=0;c<5;c++){
      float4 wv = *(const float4*)&wp[c][i*4];
      acc[c] += xv.x*wv.x + xv.y*wv.y + xv.z*wv.z + xv.w*wv.w;
    }
  }
  // scatter: cols 0..5 -> sp (LDS), 6..21 -> B, 22..37 -> C
  size_t kbL = (size_t)kb*LN;
  int loc = loc0 + rowg;
  #pragma unroll
  for (int c=0;c<5;c++){
    int col = colg*5 + c;
    float v = acc[c];
    if (col < DTR)               sp[rowg*8 + col] = v;
    else if (col < DTR+NST)      Bsp[(kbL+loc)*NST + (col-DTR)] = v;
    else if (col < CPROJ)        Csp[(kbL+loc)*NST + (col-DTR-NST)] = v;
  }
  __syncthreads();
  // epilogue: delta = softplus(dtb + sp . dtw^T)
  const float* dtbk = dtb + (size_t)k*DIN;
  for (int o = t; o < 32*DIN; o += 256){
    int li = o / DIN, d = o % DIN;
    float a = dtbk[d];
    const float* pr = &sp[li*8];
    #pragma unroll
    for (int r=0;r<DTR;r++) a += pr[r]*sdt[r*DIN + d];
    delta[(kbL + loc0 + li)*DIN + d] = softplus_f(a);
  }
}

// ---------------- K4: scan pass 1 — per-chunk summaries (P = prod dA, Hc = local end state) ----------------
__global__ __launch_bounds__(192) void k4_pass1(const float* __restrict__ delta,
    const float* __restrict__ xc, const float* __restrict__ Bsp,
    const float* __restrict__ A_logs,
    float* __restrict__ Pc, float* __restrict__ Hc){
  __shared__ float sB[CL*NST];
  int d = threadIdx.x;
  int c = blockIdx.x, b = blockIdx.y, k = blockIdx.z;
  int kb = k*BN + b;
  for (int i = d; i < CL*NST; i += 192){
    int sl = i / NST, n = i % NST;
    int loc = seq_to_loc(k, c*CL + sl);
    sB[i] = Bsp[((size_t)kb*LN + loc)*NST + n];
  }
  float A[NST];
  const float* ap = A_logs + ((size_t)k*DIN + d)*NST;
  #pragma unroll
  for (int n=0;n<NST;n++) A[n] = -__expf(ap[n]);
  __syncthreads();
  float h[NST], P[NST];
  #pragma unroll
  for (int n=0;n<NST;n++){ h[n]=0.f; P[n]=1.f; }
  const float* dp = delta + (size_t)kb*LN*DIN + d;
  const float* up = xc + (size_t)b*LN*DIN + d;
  for (int sl = 0; sl < CL; sl++){
    int loc = seq_to_loc(k, c*CL + sl);
    float dl = dp[(size_t)loc*DIN];
    float uu = up[(size_t)loc*DIN];
    float du = dl * uu;
    const float* bb = sB + sl*NST;
    #pragma unroll
    for (int n=0;n<NST;n++){
      float e = __expf(dl * A[n]);
      h[n] = e*h[n] + du*bb[n];
      P[n] *= e;
    }
  }
  size_t base = (((size_t)kb*NC + c)*DIN + d)*NST;
  #pragma unroll
  for (int n=0;n<NST;n++){ Pc[base+n] = P[n]; Hc[base+n] = h[n]; }
}

// ---------------- K5: scan pass 2 — compose chunk summaries; writes h_in over Pc (alias) ----------------
__global__ __launch_bounds__(256) void k5_pass2(float* __restrict__ Pc,
    const float* __restrict__ Hc){
  int idx = blockIdx.x*256 + threadIdx.x;
  if (idx >= KD*BN*DIN*NST) return;
  int kb = idx / (DIN*NST);
  int dn = idx % (DIN*NST);
  size_t base = (size_t)kb*NC*DIN*NST + dn;
  float h = 0.f;
  for (int c = 0; c < NC; c++){
    size_t o = base + (size_t)c*DIN*NST;
    float p = Pc[o];
    float hv = Hc[o];
    Pc[o] = h;          // store h_in for chunk c
    h = p*h + hv;
  }
}

// ---------------- K6: scan pass 3 — recompute with correct h_in, emit y ----------------
__global__ __launch_bounds__(192) void k6_pass3(const float* __restrict__ delta,
    const float* __restrict__ xc, const float* __restrict__ Bsp,
    const float* __restrict__ Csp, const float* __restrict__ A_logs,
    const float* __restrict__ hin, float* __restrict__ ysum){
  __shared__ float sB[CL*NST];
  __shared__ float sC[CL*NST];
  int d = threadIdx.x;
  int c = blockIdx.x, b = blockIdx.y, k = blockIdx.z;
  int kb = k*BN + b;
  for (int i = d; i < CL*NST; i += 192){
    int sl = i / NST, n = i % NST;
    int loc = seq_to_loc(k, c*CL + sl);
    sB[i] = Bsp[((size_t)kb*LN + loc)*NST + n];
    sC[i] = Csp[((size_t)kb*LN + loc)*NST + n];
  }
  float A[NST];
  const float* ap = A_logs + ((size_t)k*DIN + d)*NST;
  #pragma unroll
  for (int n=0;n<NST;n++) A[n] = -__expf(ap[n]);
  float h[NST];
  size_t hb = (((size_t)kb*NC + c)*DIN + d)*NST;
  #pragma unroll
  for (int n=0;n<NST;n++) h[n] = hin[hb+n];
  __syncthreads();
  const float* dp = delta + (size_t)kb*LN*DIN + d;
  const float* up = xc + (size_t)b*LN*DIN + d;
  float* yp = ysum + (size_t)b*LN*DIN + d;
  for (int sl = 0; sl < CL; sl++){
    int loc = seq_to_loc(k, c*CL + sl);
    float dl = dp[(size_t)loc*DIN];
    float uu = up[(size_t)loc*DIN];
    float du = dl * uu;
    const float* bb = sB + sl*NST;
    const float* cc2 = sC + sl*NST;
    float y = 0.f;
    #pragma unroll
    for (int n=0;n<NST;n++){
      float e = __expf(dl * A[n]);
      h[n] = e*h[n] + du*bb[n];
      y += h[n]*cc2[n];
    }
    atomicAdd(&yp[(size_t)loc*DIN], y);
  }
}

// ---------------- K7: LayerNorm + gate(silu z) + out_proj (96x192) ----------------
// ow staged in LDS (coalesced once per block); pad 193 => read sow[cc*193+i] is a
// 2-way bank alias (free), sg read is broadcast. Same math as before.
__global__ __launch_bounds__(256) void k7_out(const float* __restrict__ ysum,
    const float* __restrict__ sz, const float* __restrict__ gamma,
    const float* __restrict__ beta, const float* __restrict__ ow,
    float* __restrict__ out){
  __shared__ float sg[8*192];
  __shared__ float sow[96*193];
  int t = threadIdx.x;
  // stage ow coalesced (96x192)
  for (int f = t; f < DMODEL*DIN; f += 256){
    int row = f / DIN, col = f % DIN;
    sow[row*193 + col] = ow[f];
  }
  int m0 = blockIdx.x * 8;
  int li = t >> 5;
  int j  = t & 31;
  int m = m0 + li;
  const float* yr = ysum + (size_t)m*DIN;
  float vals[6];
  float s1 = 0.f, s2 = 0.f;
  #pragma unroll
  for (int q=0;q<6;q++){
    float v = yr[j + 32*q];
    vals[q] = v; s1 += v; s2 += v*v;
  }
  #pragma unroll
  for (int off=16; off>=1; off>>=1){
    s1 += __shfl_xor(s1, off);
    s2 += __shfl_xor(s2, off);
  }
  float mu  = s1 * (1.0f/192.0f);
  float var = s2 * (1.0f/192.0f) - mu*mu;
  float rstd = rsqrtf(var + 1e-5f);
  const float* zr = sz + (size_t)m*DIN;
  #pragma unroll
  for (int q=0;q<6;q++){
    int dd = j + 32*q;
    float v = (vals[q]-mu)*rstd*gamma[dd] + beta[dd];
    sg[li*192 + dd] = v * zr[dd];
  }
  __syncthreads();
  for (int o = t; o < 8*DMODEL; o += 256){
    int lo = o / DMODEL; int cc = o % DMODEL;
    const float* gr = sg + lo*192;
    const float* wr = sow + cc*193;
    float a = 0.f;
    #pragma unroll 8
    for (int i=0;i<192;i++){
      a += gr[i]*wr[i];
    }
    out[(size_t)(m0+lo)*DMODEL + cc] = a;
  }
}

extern "C" void kernel_launch(void* const* d_in, const int* in_sizes, int n_in,
                              void* d_out, int out_size, void* d_ws, size_t ws_size,
                              hipStream_t stream){
  (void)in_sizes; (void)n_in; (void)out_size; (void)ws_size;
  const float* x    = (const float*)d_in[0];
  const float* ipw  = (const float*)d_in[1];
  const float* cw   = (const float*)d_in[2];
  const float* cb   = (const float*)d_in[3];
  const float* xpw  = (const float*)d_in[4];
  const float* dtw  = (const float*)d_in[5];
  const float* dtb  = (const float*)d_in[6];
  const float* alog = (const float*)d_in[7];
  const float* Ds   = (const float*)d_in[8];
  const float* gam  = (const float*)d_in[9];
  const float* bet  = (const float*)d_in[10];
  const float* ow   = (const float*)d_in[11];
  float* out = (float*)d_out;

  float* ws = (float*)d_ws;
  const size_t BLD  = (size_t)BN*LN*DIN;          // 2,408,448
  const size_t KBLN = (size_t)KD*BN*LN*NST;       //   802,816
  const size_t SUMN = (size_t)KD*BN*NC*DIN*NST;   // 2,752,512

  float* xc    = ws;
  float* sz    = ws + BLD;
  float* ysum  = ws + 2*BLD;
  float* delta = ws + 3*BLD;        // 4*BLD
  float* xi    = delta;             // alias: xi dead once K2 done, K3 overwrites with delta
  float* Bsp   = ws + 7*BLD;
  float* Csp   = Bsp + KBLN;
  float* Pc    = Csp + KBLN;        // pass2 overwrites Pc with h_in (per-thread read-then-write)
  float* Hc    = Pc + SUMN;

  k1_inproj<<<dim3(392,4), 256, 0, stream>>>(x, ipw, xi, sz);
  k2_conv<<<2352, 256, 0, stream>>>(xi, cw, cb, Ds, xc, ysum);
  k3_proj<<<dim3(98,4,4), 256, 0, stream>>>(xc, xpw, dtw, dtb, delta, Bsp, Csp);
  k4_pass1<<<dim3(NC,4,4), 192, 0, stream>>>(delta, xc, Bsp, alog, Pc, Hc);
  k5_pass2<<<192, 256, 0, stream>>>(Pc, Hc);
  k6_pass3<<<dim3(NC,4,4), 192, 0, stream>>>(delta, xc, Bsp, Csp, alog, Pc, ysum);
  k7_out<<<1568, 256, 0, stream>>>(ysum, sz, gam, bet, ow, out);
}

// Round 13
// 354.753 us; speedup vs baseline: 1.4120x; 1.4120x over previous
//
#include <hip/hip_runtime.h>
#include <math.h>

#define HN 56
#define WN 56
#define LN 3136
#define BN 4
#define DIN 192
#define NST 16
#define KD 4
#define DTR 6
#define CPROJ 38
#define CL 56
#define NC 56
#define DMODEL 96

__device__ __forceinline__ float silu_f(float x){ return x / (1.0f + __expf(-x)); }
__device__ __forceinline__ float softplus_f(float x){ return (x > 20.0f) ? x : log1pf(__expf(x)); }

// sequence position s of direction k -> row-major spatial location
__device__ __forceinline__ int seq_to_loc(int k, int s){
  int ss = (k & 2) ? (LN - 1 - s) : s;
  if (k & 1) { int h = ss % HN; int w = ss / HN; return h * WN + w; }
  return ss;
}

// ---------------- K1: in_proj GEMM (12544 x 384, K=96) ----------------
__global__ __launch_bounds__(256) void k1_inproj(const float* __restrict__ x,
    const float* __restrict__ w, float* __restrict__ xi, float* __restrict__ sz){
  __shared__ float sx[32*100];   // padded stride 100 to avoid bank conflicts
  __shared__ float sw[96*100];
  int t = threadIdx.x;
  int m0 = blockIdx.x * 32;          // row tile
  int g  = blockIdx.y;               // col group: cols g*96 .. g*96+95
  const float* xb = x + (size_t)m0 * 96;
  const float* wb = w + (size_t)g * 96 * 96;
  for (int i = t; i < 32*96; i += 256) sx[(i/96)*100 + (i%96)] = xb[i];
  for (int i = t; i < 96*96; i += 256) sw[(i/96)*100 + (i%96)] = wb[i];
  __syncthreads();
  int li0 = (t & 7) * 4;
  int c0  = (t >> 3) * 3;
  float acc[4][3];
  #pragma unroll
  for (int j=0;j<4;j++){ acc[j][0]=0.f; acc[j][1]=0.f; acc[j][2]=0.f; }
  for (int i = 0; i < 96; i += 4) {
    float4 xv[4], wv[3];
    #pragma unroll
    for (int j=0;j<4;j++) xv[j] = *(const float4*)&sx[(li0+j)*100 + i];
    #pragma unroll
    for (int m=0;m<3;m++) wv[m] = *(const float4*)&sw[(c0+m)*100 + i];
    #pragma unroll
    for (int j=0;j<4;j++){
      #pragma unroll
      for (int m=0;m<3;m++){
        acc[j][m] += xv[j].x*wv[m].x + xv[j].y*wv[m].y + xv[j].z*wv[m].z + xv[j].w*wv[m].w;
      }
    }
  }
  #pragma unroll
  for (int j=0;j<4;j++){
    int row = m0 + li0 + j;
    #pragma unroll
    for (int m=0;m<3;m++){
      int o = g*96 + c0 + m;
      float v = acc[j][m];
      if (o < DIN) xi[(size_t)row*DIN + o] = v;
      else         sz[(size_t)row*DIN + (o - DIN)] = silu_f(v);
    }
  }
}

// ---------------- K2: depthwise conv 3x3 + silu; also y_init = xc * sum_k D ----------------
__global__ __launch_bounds__(256) void k2_conv(const float* __restrict__ xi,
    const float* __restrict__ cw, const float* __restrict__ cb,
    const float* __restrict__ Ds,
    float* __restrict__ xc, float* __restrict__ ysum){
  int t = blockIdx.x * 256 + threadIdx.x;
  const int total = BN * LN * (DIN/4);
  if (t >= total) return;
  int c4 = t % (DIN/4); int m = t / (DIN/4);
  int c = c4 * 4;
  int b = m / LN; int loc = m % LN;
  int h = loc / WN; int w = loc % WN;
  float acc[4];
  #pragma unroll
  for (int j=0;j<4;j++) acc[j] = cb[c+j];
  float wgt[4][9];
  #pragma unroll
  for (int j=0;j<4;j++)
    #pragma unroll
    for (int q=0;q<9;q++) wgt[j][q] = cw[(c+j)*9 + q];
  for (int dh=-1; dh<=1; dh++){
    int hh = h + dh; if (hh < 0 || hh >= HN) continue;
    for (int dw=-1; dw<=1; dw++){
      int ww = w + dw; if (ww < 0 || ww >= WN) continue;
      const float4 xv = *(const float4*)&xi[((size_t)(b*LN + hh*WN + ww))*DIN + c];
      int q = (dh+1)*3 + (dw+1);
      acc[0] += xv.x * wgt[0][q];
      acc[1] += xv.y * wgt[1][q];
      acc[2] += xv.z * wgt[2][q];
      acc[3] += xv.w * wgt[3][q];
    }
  }
  float4 xcv, yv;
  #pragma unroll
  for (int j=0;j<4;j++){
    float v = silu_f(acc[j]);
    float sd = Ds[c+j] + Ds[DIN + c+j] + Ds[2*DIN + c+j] + Ds[3*DIN + c+j];
    ((float*)&xcv)[j] = v;
    ((float*)&yv)[j]  = v * sd;
  }
  *(float4*)&xc[(size_t)m*DIN + c]   = xcv;
  *(float4*)&ysum[(size_t)m*DIN + c] = yv;
}

// ---------------- K3 v5b: x_proj (38x192) + dt_proj + softplus ----------------
// Measured lessons: W MUST come from LDS (v4's global W: 228us); residency was
// v3's limiter (20.9% occ, 94.9us). v5b: W K-split into two 38x96 LDS chunks,
// stride 100 (multiple of 4 -> float4-aligned; banks (20*colg+4c) mod 32 all
// distinct -> conflict-free). LDS ~20.8KB -> 7 blk/CU by LDS; 32-loc tiles ->
// grid 1568 (6.1 blk/CU). X streamed from global (L2-resident).
__global__ __launch_bounds__(256, 6) void k3_proj(const float* __restrict__ xc,
    const float* __restrict__ xpw,   // (4,38,192)
    const float* __restrict__ dtw,   // (4,192,6)
    const float* __restrict__ dtb,   // (4,192)
    float* __restrict__ delta, float* __restrict__ Bsp, float* __restrict__ Csp){
  __shared__ float sw[38*100];   // one K-half of W, padded stride 100 (16B-aligned rows)
  __shared__ float sdt[DTR*DIN]; // transposed dt_projs_weight
  __shared__ float sp[32*8];
  int t = threadIdx.x;
  int loc0 = blockIdx.x * 32;
  int b = blockIdx.y;
  int k = blockIdx.z;
  int kb = k*BN + b;
  const float* wk   = xpw + (size_t)k*CPROJ*DIN;
  const float* dtwk = dtw + (size_t)k*DIN*DTR;
  int rowg = t >> 3;   // 0..31 -> one loc each
  int colg = t & 7;    // 0..7  -> cols colg*5..colg*5+4 (cols 38,39 clamped, discarded)
  int coff[5];
  #pragma unroll
  for (int c=0;c<5;c++){
    int col = colg*5 + c;
    coff[c] = (col < CPROJ ? col : CPROJ-1)*100;
  }
  float acc[5];
  #pragma unroll
  for (int c=0;c<5;c++) acc[c] = 0.f;
  const float* xr = xc + ((size_t)b*LN + loc0 + rowg)*DIN;
  for (int ck = 0; ck < 2; ck++){
    // stage W half (38 rows x 24 float4), coalesced
    for (int f = t; f < 38*24; f += 256){
      int row = f / 24, cf = f % 24;
      *(float4*)&sw[row*100 + cf*4] = *(const float4*)&wk[(size_t)row*DIN + ck*96 + cf*4];
    }
    if (ck == 0){
      for (int f = t; f < DIN*DTR; f += 256){
        int d = f / DTR, r = f % DTR;
        sdt[r*DIN + d] = dtwk[f];
      }
    }
    __syncthreads();
    #pragma unroll 6
    for (int i = 0; i < 24; i++){
      float4 xv = *(const float4*)&xr[ck*96 + i*4];
      #pragma unroll
      for (int c=0;c<5;c++){
        float4 wv = *(const float4*)&sw[coff[c] + i*4];
        acc[c] += xv.x*wv.x + xv.y*wv.y + xv.z*wv.z + xv.w*wv.w;
      }
    }
    __syncthreads();   // protect sw restage (ck=0) / separate compute from scatter (ck=1)
  }
  // scatter: cols 0..5 -> sp (LDS), 6..21 -> B, 22..37 -> C
  size_t kbL = (size_t)kb*LN;
  int loc = loc0 + rowg;
  #pragma unroll
  for (int c=0;c<5;c++){
    int col = colg*5 + c;
    float v = acc[c];
    if (col < DTR)               sp[rowg*8 + col] = v;
    else if (col < DTR+NST)      Bsp[(kbL+loc)*NST + (col-DTR)] = v;
    else if (col < CPROJ)        Csp[(kbL+loc)*NST + (col-DTR-NST)] = v;
  }
  __syncthreads();
  // epilogue: delta = softplus(dtb + sp . dtw^T)
  const float* dtbk = dtb + (size_t)k*DIN;
  for (int o = t; o < 32*DIN; o += 256){
    int li = o / DIN, d = o % DIN;
    float a = dtbk[d];
    const float* pr = &sp[li*8];
    #pragma unroll
    for (int r=0;r<DTR;r++) a += pr[r]*sdt[r*DIN + d];
    delta[(kbL + loc0 + li)*DIN + d] = softplus_f(a);
  }
}

// ---------------- K4: scan pass 1 — per-chunk summaries (P = prod dA, Hc = local end state) ----------------
__global__ __launch_bounds__(192) void k4_pass1(const float* __restrict__ delta,
    const float* __restrict__ xc, const float* __restrict__ Bsp,
    const float* __restrict__ A_logs,
    float* __restrict__ Pc, float* __restrict__ Hc){
  __shared__ float sB[CL*NST];
  int d = threadIdx.x;
  int c = blockIdx.x, b = blockIdx.y, k = blockIdx.z;
  int kb = k*BN + b;
  for (int i = d; i < CL*NST; i += 192){
    int sl = i / NST, n = i % NST;
    int loc = seq_to_loc(k, c*CL + sl);
    sB[i] = Bsp[((size_t)kb*LN + loc)*NST + n];
  }
  float A[NST];
  const float* ap = A_logs + ((size_t)k*DIN + d)*NST;
  #pragma unroll
  for (int n=0;n<NST;n++) A[n] = -__expf(ap[n]);
  __syncthreads();
  float h[NST], P[NST];
  #pragma unroll
  for (int n=0;n<NST;n++){ h[n]=0.f; P[n]=1.f; }
  const float* dp = delta + (size_t)kb*LN*DIN + d;
  const float* up = xc + (size_t)b*LN*DIN + d;
  for (int sl = 0; sl < CL; sl++){
    int loc = seq_to_loc(k, c*CL + sl);
    float dl = dp[(size_t)loc*DIN];
    float uu = up[(size_t)loc*DIN];
    float du = dl * uu;
    const float* bb = sB + sl*NST;
    #pragma unroll
    for (int n=0;n<NST;n++){
      float e = __expf(dl * A[n]);
      h[n] = e*h[n] + du*bb[n];
      P[n] *= e;
    }
  }
  size_t base = (((size_t)kb*NC + c)*DIN + d)*NST;
  #pragma unroll
  for (int n=0;n<NST;n++){ Pc[base+n] = P[n]; Hc[base+n] = h[n]; }
}

// ---------------- K5: scan pass 2 — compose chunk summaries; writes h_in over Pc (alias) ----------------
__global__ __launch_bounds__(256) void k5_pass2(float* __restrict__ Pc,
    const float* __restrict__ Hc){
  int idx = blockIdx.x*256 + threadIdx.x;
  if (idx >= KD*BN*DIN*NST) return;
  int kb = idx / (DIN*NST);
  int dn = idx % (DIN*NST);
  size_t base = (size_t)kb*NC*DIN*NST + dn;
  float h = 0.f;
  for (int c = 0; c < NC; c++){
    size_t o = base + (size_t)c*DIN*NST;
    float p = Pc[o];
    float hv = Hc[o];
    Pc[o] = h;          // store h_in for chunk c
    h = p*h + hv;
  }
}

// ---------------- K6: scan pass 3 — recompute with correct h_in, emit y ----------------
__global__ __launch_bounds__(192) void k6_pass3(const float* __restrict__ delta,
    const float* __restrict__ xc, const float* __restrict__ Bsp,
    const float* __restrict__ Csp, const float* __restrict__ A_logs,
    const float* __restrict__ hin, float* __restrict__ ysum){
  __shared__ float sB[CL*NST];
  __shared__ float sC[CL*NST];
  int d = threadIdx.x;
  int c = blockIdx.x, b = blockIdx.y, k = blockIdx.z;
  int kb = k*BN + b;
  for (int i = d; i < CL*NST; i += 192){
    int sl = i / NST, n = i % NST;
    int loc = seq_to_loc(k, c*CL + sl);
    sB[i] = Bsp[((size_t)kb*LN + loc)*NST + n];
    sC[i] = Csp[((size_t)kb*LN + loc)*NST + n];
  }
  float A[NST];
  const float* ap = A_logs + ((size_t)k*DIN + d)*NST;
  #pragma unroll
  for (int n=0;n<NST;n++) A[n] = -__expf(ap[n]);
  float h[NST];
  size_t hb = (((size_t)kb*NC + c)*DIN + d)*NST;
  #pragma unroll
  for (int n=0;n<NST;n++) h[n] = hin[hb+n];
  __syncthreads();
  const float* dp = delta + (size_t)kb*LN*DIN + d;
  const float* up = xc + (size_t)b*LN*DIN + d;
  float* yp = ysum + (size_t)b*LN*DIN + d;
  for (int sl = 0; sl < CL; sl++){
    int loc = seq_to_loc(k, c*CL + sl);
    float dl = dp[(size_t)loc*DIN];
    float uu = up[(size_t)loc*DIN];
    float du = dl * uu;
    const float* bb = sB + sl*NST;
    const float* cc2 = sC + sl*NST;
    float y = 0.f;
    #pragma unroll
    for (int n=0;n<NST;n++){
      float e = __expf(dl * A[n]);
      h[n] = e*h[n] + du*bb[n];
      y += h[n]*cc2[n];
    }
    atomicAdd(&yp[(size_t)loc*DIN], y);
  }
}

// ---------------- K7: LayerNorm + gate(silu z) + out_proj (96x192) ----------------
// ow staged in LDS (coalesced once per block); pad 193 => read sow[cc*193+i] is a
// 2-way bank alias (free), sg read is broadcast. Same math as before.
__global__ __launch_bounds__(256) void k7_out(const float* __restrict__ ysum,
    const float* __restrict__ sz, const float* __restrict__ gamma,
    const float* __restrict__ beta, const float* __restrict__ ow,
    float* __restrict__ out){
  __shared__ float sg[8*192];
  __shared__ float sow[96*193];
  int t = threadIdx.x;
  // stage ow coalesced (96x192)
  for (int f = t; f < DMODEL*DIN; f += 256){
    int row = f / DIN, col = f % DIN;
    sow[row*193 + col] = ow[f];
  }
  int m0 = blockIdx.x * 8;
  int li = t >> 5;
  int j  = t & 31;
  int m = m0 + li;
  const float* yr = ysum + (size_t)m*DIN;
  float vals[6];
  float s1 = 0.f, s2 = 0.f;
  #pragma unroll
  for (int q=0;q<6;q++){
    float v = yr[j + 32*q];
    vals[q] = v; s1 += v; s2 += v*v;
  }
  #pragma unroll
  for (int off=16; off>=1; off>>=1){
    s1 += __shfl_xor(s1, off);
    s2 += __shfl_xor(s2, off);
  }
  float mu  = s1 * (1.0f/192.0f);
  float var = s2 * (1.0f/192.0f) - mu*mu;
  float rstd = rsqrtf(var + 1e-5f);
  const float* zr = sz + (size_t)m*DIN;
  #pragma unroll
  for (int q=0;q<6;q++){
    int dd = j + 32*q;
    float v = (vals[q]-mu)*rstd*gamma[dd] + beta[dd];
    sg[li*192 + dd] = v * zr[dd];
  }
  __syncthreads();
  for (int o = t; o < 8*DMODEL; o += 256){
    int lo = o / DMODEL; int cc = o % DMODEL;
    const float* gr = sg + lo*192;
    const float* wr = sow + cc*193;
    float a = 0.f;
    #pragma unroll 8
    for (int i=0;i<192;i++){
      a += gr[i]*wr[i];
    }
    out[(size_t)(m0+lo)*DMODEL + cc] = a;
  }
}

extern "C" void kernel_launch(void* const* d_in, const int* in_sizes, int n_in,
                              void* d_out, int out_size, void* d_ws, size_t ws_size,
                              hipStream_t stream){
  (void)in_sizes; (void)n_in; (void)out_size; (void)ws_size;
  const float* x    = (const float*)d_in[0];
  const float* ipw  = (const float*)d_in[1];
  const float* cw   = (const float*)d_in[2];
  const float* cb   = (const float*)d_in[3];
  const float* xpw  = (const float*)d_in[4];
  const float* dtw  = (const float*)d_in[5];
  const float* dtb  = (const float*)d_in[6];
  const float* alog = (const float*)d_in[7];
  const float* Ds   = (const float*)d_in[8];
  const float* gam  = (const float*)d_in[9];
  const float* bet  = (const float*)d_in[10];
  const float* ow   = (const float*)d_in[11];
  float* out = (float*)d_out;

  float* ws = (float*)d_ws;
  const size_t BLD  = (size_t)BN*LN*DIN;          // 2,408,448
  const size_t KBLN = (size_t)KD*BN*LN*NST;       //   802,816
  const size_t SUMN = (size_t)KD*BN*NC*DIN*NST;   // 2,752,512

  float* xc    = ws;
  float* sz    = ws + BLD;
  float* ysum  = ws + 2*BLD;
  float* delta = ws + 3*BLD;        // 4*BLD
  float* xi    = delta;             // alias: xi dead once K2 done, K3 overwrites with delta
  float* Bsp   = ws + 7*BLD;
  float* Csp   = Bsp + KBLN;
  float* Pc    = Csp + KBLN;        // pass2 overwrites Pc with h_in (per-thread read-then-write)
  float* Hc    = Pc + SUMN;

  k1_inproj<<<dim3(392,4), 256, 0, stream>>>(x, ipw, xi, sz);
  k2_conv<<<2352, 256, 0, stream>>>(xi, cw, cb, Ds, xc, ysum);
  k3_proj<<<dim3(98,4,4), 256, 0, stream>>>(xc, xpw, dtw, dtb, delta, Bsp, Csp);
  k4_pass1<<<dim3(NC,4,4), 192, 0, stream>>>(delta, xc, Bsp, alog, Pc, Hc);
  k5_pass2<<<192, 256, 0, stream>>>(Pc, Hc);
  k6_pass3<<<dim3(NC,4,4), 192, 0, stream>>>(delta, xc, Bsp, Csp, alog, Pc, ysum);
  k7_out<<<1568, 256, 0, stream>>>(ysum, sz, gam, bet, ow, out);
}